// Round 2
// baseline (643.184 us; speedup 1.0000x reference)
//
#include <hip/hip_runtime.h>

// QuantumQLSTM on MI355X — R13 (= R12 resubmit; R12 hit an infra failure,
// "MI355X container failed twice", before any bench/profile ran).
// Structure (R7+): outs[t,b,:] = Hv[t,:] (b-independent). zx precompute ->
// 1-block sequential rec -> broadcast.
//
// R11 post-mortem: rec = 354us = ~1660 cyc/step; chain = 2 barriers + 3 LDS
// roundtrips (Hbuf write->read ~120cy, zh write->read ~120cy). R12/R13:
// re-pair threads as half=lane>>5 so each lane holds Hnew for its h in a
// register and contributes 6 matvec columns directly: 6 fma + 5-level DPP
// reduce stopped at 32 lanes (lane31 = cols0-5 partial, lane63 = cols6-11),
// cross-wave combine via ds_add_f32 into triple-buffered zh[3][2][8] (read
// t%3, accum (t+1)%3, zero (t+2)%3). Hbuf eliminated; ONE lds_barrier per
// step; gate exchange via __shfl_xor(,32). Predicted ~190-230us rec.
//
// History: R1 4250 -> R2 2010 -> R3 1516 -> R4 1443 -> R5 1426 -> R6 FAILED
// -> R7 758 (rec 484) -> R8 772 (498) -> R9 752 (477) -> R10 744 (468)
// -> R11 632 (rec 354) -> R12 infra-fail -> R13 (resubmit).

#define T_DIM 512
#define B_DIM 256
#define D_DIM 256
#define H_DIM 256
#define DH    512   // D + H
#define NG    16    // 4 gates * NQ(4)
#define PAD   260   // zx LDS row stride

__device__ __forceinline__ float fast_sigmoid(float x) {
    return 1.0f / (1.0f + __expf(-x));
}
__device__ __forceinline__ float fast_tanh(float x) {
    // |x| <= ~2.1 here (|C| <= 0.557/(1-0.731)); exp safe
    float e = __expf(2.0f * x);
    return (e - 1.0f) / (e + 1.0f);
}
// x + dpp_mov(x): one reduction level, VALU pipe.
template <int CTRL, int RM, int BM, bool BC>
__device__ __forceinline__ float dadd(float x) {
    return x + __int_as_float(
        __builtin_amdgcn_update_dpp(0, __float_as_int(x), CTRL, RM, BM, BC));
}
// 32-lane-group sum: lane31 = sum(lanes 0..31), lane63 = sum(lanes 32..63).
// (wave-sum minus the final bcast31 level — keeps the two halves separate.)
__device__ __forceinline__ float rsum32(float x) {
    x = dadd<0x111, 0xf, 0xf, true >(x);   // row_shr:1
    x = dadd<0x112, 0xf, 0xf, true >(x);   // row_shr:2
    x = dadd<0x114, 0xf, 0xf, true >(x);   // row_shr:4
    x = dadd<0x118, 0xf, 0xf, true >(x);   // row_shr:8
    x = dadd<0x142, 0xa, 0xf, false>(x);   // row_bcast:15 -> lanes 31, 63
    return x;
}
// Barrier draining ONLY the LDS pipe (no vmcnt): global ops float across steps.
__device__ __forceinline__ void lds_barrier() {
    __asm__ volatile("s_waitcnt lgkmcnt(0)\n\ts_barrier" ::: "memory");
}

// -------------------- zx precompute: zx[(t*B+b)*16+q] = b_q + phi_q + x.Wx[q,:]
// (phi folded into bias; verified R10 kernel, unchanged)
__global__ __launch_bounds__(256) void zx_kernel(
    const float* __restrict__ x,
    const float* __restrict__ Wf, const float* __restrict__ Wi,
    const float* __restrict__ Wu, const float* __restrict__ Wo,
    const float* __restrict__ bf, const float* __restrict__ bi,
    const float* __restrict__ bu, const float* __restrict__ bo,
    const float* __restrict__ phf, const float* __restrict__ phi,
    const float* __restrict__ phu, const float* __restrict__ pho,
    float* __restrict__ zx)
{
    __shared__ float Wl[NG][PAD];
    __shared__ float Xl[16][PAD];
    const int tid = threadIdx.x;

    for (int e = tid; e < NG * 64; e += 256) {
        int q16 = e >> 6, c4 = (e & 63) * 4;
        int g = q16 >> 2, qj = q16 & 3;
        const float* W = (g == 0) ? Wf : (g == 1) ? Wi : (g == 2) ? Wu : Wo;
        *(float4*)&Wl[q16][c4] = *(const float4*)(W + qj * DH + c4);
    }
    const long base = (long)blockIdx.x * 16 * D_DIM;
    for (int e = tid; e < 16 * 64; e += 256) {
        int r = e >> 6, c4 = (e & 63) * 4;
        *(float4*)&Xl[r][c4] = *(const float4*)(x + base + r * D_DIM + c4);
    }
    __syncthreads();

    const int q16 = tid & 15, r = tid >> 4;
    const int g = q16 >> 2, qj = q16 & 3;
    const float* bv = (g == 0) ? bf : (g == 1) ? bi : (g == 2) ? bu : bo;
    const float* pv = (g == 0) ? phf : (g == 1) ? phi : (g == 2) ? phu : pho;
    float acc = bv[qj] + pv[qj];
    #pragma unroll 4
    for (int k = 0; k < D_DIM; k += 4) {
        float4 xv = *(float4*)&Xl[r][k];
        float4 wv = *(float4*)&Wl[q16][k];
        acc += xv.x * wv.x + xv.y * wv.y + xv.z * wv.z + xv.w * wv.w;
    }
    zx[(long)blockIdx.x * 256 + tid] = acc;
}

// -------------------- sequential core: ONE block, 512 threads (8 waves)
// Thread (wv, lane): h = wv*32 + (lane&31); half = lane>>5 (0: f,i  1: u,o).
// Both halves of a lane-pair compute C/Hnew redundantly (bit-identical);
// half0 contributes matvec cols 0-5, half1 cols 6-11, from Hnew in-register.
__global__ __launch_bounds__(512) void rec_kernel(
    const float* __restrict__ Wf, const float* __restrict__ Wi,
    const float* __restrict__ Wu, const float* __restrict__ Wo,
    const float* __restrict__ zx,
    float* __restrict__ hv_tab,   // [T][H]; hv_tab[-H..-1] is a scratch pad row
    float* __restrict__ c_fin)    // [H]
{
    __shared__ float zh_s[3][2][8];        // [buf][half][6 used, pad to 8]
    const int tid  = threadIdx.x;          // 0..511
    const int lane = tid & 63;
    const int wv   = tid >> 6;             // wave 0..7
    const int l31  = lane & 31;
    const int half = lane >> 5;            // 0: f,i (cols 0-5)  1: u,o (cols 6-11)
    const int h    = wv * 32 + l31;        // 0..255

    // 6 recurrent-weight scalars for this lane's columns c = half*6+k
    float W6[6];
    #pragma unroll
    for (int k = 0; k < 6; ++k) {
        const int c = half * 6 + k;
        const int g = c / 3, j = c % 3 + 1;
        const float* Wg = (g == 0) ? Wf : (g == 1) ? Wi : (g == 2) ? Wu : Wo;
        W6[k] = Wg[j * DH + 256 + h];
    }

    if (tid < 48) ((float*)zh_s)[tid] = 0.0f;   // zero all 3 buffers

    float C = 0.0f, Hprev = 0.0f;

    // zx register double-buffer (depth 2): thread reads its half's 2 float4
    float4 za0, za1, zb0, zb1;
    {
        const float4* p0 = (const float4*)(zx + (long)h * NG) + half * 2;
        const float4* p1 = (const float4*)(zx + ((long)B_DIM + h) * NG) + half * 2;
        za0 = p0[0]; za1 = p0[1];
        zb0 = p1[0]; zb1 = p1[1];
    }
    lds_barrier();                         // zh zero-init visible

    auto step = [&](int t, float4& z0, float4& z1) {
        const int rb = t % 3;              // read buf (accumulated at t-1)
        const int wb = (t + 1) % 3;        // accumulate for t+1 (pre-zeroed)
        const int zb = (t + 2) % 3;        // zero for t+2 (last read at t-1)

        // ---- read this step's zh first (longest-latency dependence)
        const float4 ZA = *(const float4*)&zh_s[rb][half][0];
        const float2 ZB = *(const float2*)&zh_s[rb][half][4];

        // early-issue global store of Hv[t-1] (half1 lanes; acks float)
        if (half) hv_tab[(long)(t - 1) * H_DIM + h] = Hprev;
        // zero the t+2 buffer (distinct from rb and wb; races with nothing)
        if (wv == 0 && lane < 16) zh_s[zb][lane >> 3][lane & 7] = 0.0f;

        // ---- gates: this thread's 2 gates (half0: f,i ; half1: u,o)
        const float c1 = __cosf(z0.y + ZA.x), c2 = __cosf(z0.z + ZA.y), c3 = __cosf(z0.w + ZA.z);
        const float c4 = __cosf(z1.y + ZA.w), c5 = __cosf(z1.z + ZB.x), c6 = __cosf(z1.w + ZB.y);
        const float pA = c1 * c2 * c3, pB = c4 * c5 * c6;
        float gA, gB;
        if (half == 0) { gA = fast_sigmoid(pA); gB = fast_sigmoid(pB); }   // f, i
        else           { gA = fast_tanh(pA);    gB = fast_sigmoid(pB); }   // g, o
        const float oA = __shfl_xor(gA, 32);   // partner half's first value
        const float oB = __shfl_xor(gB, 32);   // partner half's second value
        const float f_ = half ? oA : gA;
        const float i_ = half ? oB : gB;
        const float g_ = half ? gA : oA;
        const float o_ = half ? gB : oB;

        // prefetch zx[t+2] (floats across steps)
        {
            const int tp = (t + 2 < T_DIM) ? (t + 2) : t;
            const float4* pp = (const float4*)(zx + ((long)tp * B_DIM + h) * NG) + half * 2;
            z0 = pp[0]; z1 = pp[1];
        }

        C = fmaf(f_, C, i_ * g_);              // both halves redundant, bit-identical
        const float Hnew = o_ * fast_tanh(C);
        Hprev = Hnew;

        // ---- matvec from registers: 6 partials, 32-lane DPP reduce,
        //      cross-wave combine via LDS float atomics (12 addrs x 8 waves)
        const float p0 = rsum32(W6[0] * Hnew);
        const float p1 = rsum32(W6[1] * Hnew);
        const float p2 = rsum32(W6[2] * Hnew);
        const float p3 = rsum32(W6[3] * Hnew);
        const float p4 = rsum32(W6[4] * Hnew);
        const float p5 = rsum32(W6[5] * Hnew);
        if (l31 == 31) {                       // lanes 31 (cols 0-5) and 63 (cols 6-11)
            float* dst = &zh_s[wb][half][0];
            atomicAdd(dst + 0, p0); atomicAdd(dst + 1, p1);
            atomicAdd(dst + 2, p2); atomicAdd(dst + 3, p3);
            atomicAdd(dst + 4, p4); atomicAdd(dst + 5, p5);
        }
        lds_barrier();                         // the ONLY barrier per step
    };

    for (int t = 0; t < T_DIM; t += 2) {
        step(t,     za0, za1);
        step(t + 1, zb0, zb1);
    }

    if (half) {
        hv_tab[(long)(T_DIM - 1) * H_DIM + h] = Hprev;
        c_fin[h] = C;
    }
}

// -------------------- broadcast: out[t,b,:] = Hv[t,:]; tails hx=Hv[511], cx=Cfin
__global__ __launch_bounds__(256) void bc_kernel(
    const float* __restrict__ hv_tab, const float* __restrict__ c_fin,
    float* __restrict__ out)
{
    const int blk  = blockIdx.x;
    const int w    = threadIdx.x >> 6;
    const int lane = threadIdx.x & 63;

    const float* src;
    long base;
    int rbase;
    if (blk < 4 * T_DIM) {
        const int t = blk >> 2;
        rbase = (blk & 3) * 64;
        src = hv_tab + (long)t * H_DIM;
        base = (long)t * (B_DIM * H_DIM);
    } else {
        const int k = blk - 4 * T_DIM;        // 0..7
        rbase = (k & 3) * 64;
        src = (k < 4) ? (hv_tab + (long)(T_DIM - 1) * H_DIM) : c_fin;
        base = (long)T_DIM * (B_DIM * H_DIM) + (k < 4 ? 0 : (long)B_DIM * H_DIM);
    }
    const float4 v = ((const float4*)src)[lane];
    #pragma unroll
    for (int it = 0; it < 16; ++it) {
        const int row = rbase + w + 4 * it;
        ((float4*)(out + base + (long)row * H_DIM))[lane] = v;
    }
}

extern "C" void kernel_launch(void* const* d_in, const int* in_sizes, int n_in,
                              void* d_out, int out_size, void* d_ws, size_t ws_size,
                              hipStream_t stream) {
    (void)in_sizes; (void)n_in; (void)out_size; (void)ws_size;
    const float* x   = (const float*)d_in[0];
    const float* Wf  = (const float*)d_in[1];
    const float* bf  = (const float*)d_in[2];
    const float* phf = (const float*)d_in[3];
    const float* Wi  = (const float*)d_in[4];
    const float* bi  = (const float*)d_in[5];
    const float* phi = (const float*)d_in[6];
    const float* Wu  = (const float*)d_in[7];
    const float* bu  = (const float*)d_in[8];
    const float* phu = (const float*)d_in[9];
    const float* Wo  = (const float*)d_in[10];
    const float* bo  = (const float*)d_in[11];
    const float* pho = (const float*)d_in[12];

    float* zx     = (float*)d_ws;                          // T*B*16 f = 8.39 MB
    float* hv_pad = zx + (size_t)T_DIM * B_DIM * NG;       // 256 f scratch (t=0 store)
    float* hv_tab = hv_pad + H_DIM;                        // T*H f = 512 KB
    float* c_fin  = hv_tab + (size_t)T_DIM * H_DIM;        // H f = 1 KB

    zx_kernel<<<(T_DIM * B_DIM) / 16, 256, 0, stream>>>(
        x, Wf, Wi, Wu, Wo, bf, bi, bu, bo, phf, phi, phu, pho, zx);

    rec_kernel<<<1, 512, 0, stream>>>(
        Wf, Wi, Wu, Wo, zx, hv_tab, c_fin);

    bc_kernel<<<4 * T_DIM + 8, 256, 0, stream>>>(hv_tab, c_fin, (float*)d_out);
}

// Round 3
// 599.696 us; speedup vs baseline: 1.0725x; 1.0725x over previous
//
#include <hip/hip_runtime.h>

// QuantumQLSTM on MI355X — R14: rec = R11 + DPP gate-exchange; zx rewritten
// with 4x4 register tiling.
// Structure (R7+): outs[t,b,:] = Hv[t,:] (b-independent). zx precompute ->
// 1-block sequential rec -> broadcast.
//
// R13 post-mortem: single-barrier+atomics restructure NEUTRAL (365 vs 354) —
// removed LDS roundtrips == added DPP/atomic cost. rec is mixed latency+issue
// (VALUBusy ~69% of the 1 busy CU). Revert to R11; cut ONE chain segment:
// __shfl_xor(g,1) [ds_bpermute ~120cy] -> DPP quad_perm 0xB1 [~8cy VALU].
// zx: non-rec has been a constant ~278us since R7; zx floor = max(24us HBM,
// 7us FLOP). New zx: 512 blocks, thread computes 4 rows x 4 cols via k-chunked
// LDS (Xc[256][68], Wc[16][68]), 64 fma per 8 ds_read_b128. Predicted zx ~30us.
//
// History: R1 4250 -> R2 2010 -> R3 1516 -> R4 1443 -> R5 1426 -> R6 FAILED
// -> R7 758 (rec 484) -> R8 772 (498) -> R9 752 (477) -> R10 744 (468)
// -> R11 632 (rec 354) -> R12 infra -> R13 643 (rec 365, NEUTRAL) -> R14.

#define T_DIM 512
#define B_DIM 256
#define D_DIM 256
#define H_DIM 256
#define DH    512   // D + H
#define NG    16    // 4 gates * NQ(4)
#define XPAD  68    // Xc/Wc LDS row stride (floats): 16B-aligned, 2-way max

__device__ __forceinline__ float fast_sigmoid(float x) {
    return 1.0f / (1.0f + __expf(-x));
}
__device__ __forceinline__ float fast_tanh(float x) {
    // |x| <= ~2.1 here (|C| <= 0.557/(1-0.731)); exp safe
    float e = __expf(2.0f * x);
    return (e - 1.0f) / (e + 1.0f);
}
// x + dpp_mov(x): one reduction level, VALU pipe.
template <int CTRL, int RM, int BM, bool BC>
__device__ __forceinline__ float dadd(float x) {
    return x + __int_as_float(
        __builtin_amdgcn_update_dpp(0, __float_as_int(x), CTRL, RM, BM, BC));
}
// full-wave sum; result valid in lane 63
__device__ __forceinline__ float wsum(float x) {
    x = dadd<0x111, 0xf, 0xf, true >(x);   // row_shr:1
    x = dadd<0x112, 0xf, 0xf, true >(x);   // row_shr:2
    x = dadd<0x114, 0xf, 0xf, true >(x);   // row_shr:4
    x = dadd<0x118, 0xf, 0xf, true >(x);   // row_shr:8
    x = dadd<0x142, 0xa, 0xf, false>(x);   // row_bcast:15
    x = dadd<0x143, 0xc, 0xf, false>(x);   // row_bcast:31 -> lane63
    return x;
}
// lane^1 exchange on the VALU pipe: quad_perm [1,0,3,2] (replaces ds_bpermute)
__device__ __forceinline__ float dpp_xor1(float x) {
    return __int_as_float(
        __builtin_amdgcn_update_dpp(0, __float_as_int(x), 0xB1, 0xf, 0xf, true));
}
// Barrier draining ONLY the LDS pipe (no vmcnt): global ops float across steps.
__device__ __forceinline__ void lds_barrier() {
    __asm__ volatile("s_waitcnt lgkmcnt(0)\n\ts_barrier" ::: "memory");
}

// -------------------- zx precompute (R14 rewrite: 4x4 register tiling)
// zx[(t*B+b)*16+q] = b_q + phi_q + x_row . Wg[qj, 0:256]
// Block: 256 consecutive rows (one t). Thread (rt=tid>>2, qt=tid&3):
// rows {rt+64i}, wires q = 4*qt+j (gate qt, all 4 wires). k chunked by 64.
__global__ __launch_bounds__(256) void zx_kernel(
    const float* __restrict__ x,
    const float* __restrict__ Wf, const float* __restrict__ Wi,
    const float* __restrict__ Wu, const float* __restrict__ Wo,
    const float* __restrict__ bf, const float* __restrict__ bi,
    const float* __restrict__ bu, const float* __restrict__ bo,
    const float* __restrict__ phf, const float* __restrict__ phi,
    const float* __restrict__ phu, const float* __restrict__ pho,
    float* __restrict__ zx)
{
    __shared__ float Xc[256][XPAD];
    __shared__ float Wc[NG][XPAD];
    const int tid = threadIdx.x;
    const int rt  = tid >> 2;           // 0..63
    const int qt  = tid & 3;            // gate index 0..3

    // acc init = bias + phi for this thread's gate
    const float* bv = (qt == 0) ? bf : (qt == 1) ? bi : (qt == 2) ? bu : bo;
    const float* pv = (qt == 0) ? phf : (qt == 1) ? phi : (qt == 2) ? phu : pho;
    float acc[4][4];
    #pragma unroll
    for (int j = 0; j < 4; ++j) {
        const float bj = bv[j] + pv[j];
        acc[0][j] = bj; acc[1][j] = bj; acc[2][j] = bj; acc[3][j] = bj;
    }

    const long base = (long)blockIdx.x * 256 * D_DIM;

    for (int c = 0; c < 4; ++c) {                 // k-chunk of 64
        const int k0 = c * 64;
        // stage Xc: 256 rows x 16 float4
        #pragma unroll
        for (int it = 0; it < 16; ++it) {
            const int e = tid + it * 256;
            const int row = e >> 4, col4 = (e & 15) * 4;
            *(float4*)&Xc[row][col4] =
                *(const float4*)(x + base + (long)row * D_DIM + k0 + col4);
        }
        // stage Wc: 16 rows x 16 float4 (x-half of W)
        {
            const int q16 = tid >> 4, col4 = (tid & 15) * 4;
            const int g = q16 >> 2, qj = q16 & 3;
            const float* W = (g == 0) ? Wf : (g == 1) ? Wi : (g == 2) ? Wu : Wo;
            *(float4*)&Wc[q16][col4] = *(const float4*)(W + qj * DH + k0 + col4);
        }
        __syncthreads();

        #pragma unroll 4
        for (int kk = 0; kk < 16; ++kk) {
            const int k4 = kk * 4;
            float4 xv0 = *(float4*)&Xc[rt][k4];
            float4 xv1 = *(float4*)&Xc[rt +  64][k4];
            float4 xv2 = *(float4*)&Xc[rt + 128][k4];
            float4 xv3 = *(float4*)&Xc[rt + 192][k4];
            float4 wv0 = *(float4*)&Wc[4 * qt + 0][k4];
            float4 wv1 = *(float4*)&Wc[4 * qt + 1][k4];
            float4 wv2 = *(float4*)&Wc[4 * qt + 2][k4];
            float4 wv3 = *(float4*)&Wc[4 * qt + 3][k4];
            #pragma unroll
            for (int i = 0; i < 4; ++i) {
                const float4 xv = (i == 0) ? xv0 : (i == 1) ? xv1 : (i == 2) ? xv2 : xv3;
                acc[i][0] = fmaf(xv.x, wv0.x, fmaf(xv.y, wv0.y, fmaf(xv.z, wv0.z, fmaf(xv.w, wv0.w, acc[i][0]))));
                acc[i][1] = fmaf(xv.x, wv1.x, fmaf(xv.y, wv1.y, fmaf(xv.z, wv1.z, fmaf(xv.w, wv1.w, acc[i][1]))));
                acc[i][2] = fmaf(xv.x, wv2.x, fmaf(xv.y, wv2.y, fmaf(xv.z, wv2.z, fmaf(xv.w, wv2.w, acc[i][2]))));
                acc[i][3] = fmaf(xv.x, wv3.x, fmaf(xv.y, wv3.y, fmaf(xv.z, wv3.z, fmaf(xv.w, wv3.w, acc[i][3]))));
            }
        }
        __syncthreads();
    }

    // write: 4 rows x float4 of this thread's 4 wires; lanes in a wave are
    // (rt,qt) = (lane>>2, lane&3) -> addr = lane*16B: perfectly contiguous
    const long orow = (long)blockIdx.x * 256;
    #pragma unroll
    for (int i = 0; i < 4; ++i) {
        *(float4*)&zx[(orow + rt + 64 * i) * NG + qt * 4] =
            make_float4(acc[i][0], acc[i][1], acc[i][2], acc[i][3]);
    }
}

// -------------------- sequential core: ONE block, 512 threads (8 waves)
// (R11 structure; only change: gate exchange via DPP quad_perm, not shfl/LDS)
__global__ __launch_bounds__(512) void rec_kernel(
    const float* __restrict__ Wf, const float* __restrict__ Wi,
    const float* __restrict__ Wu, const float* __restrict__ Wo,
    const float* __restrict__ zx,
    float* __restrict__ hv_tab,   // [T][H]; hv_tab[-H..-1] is a scratch pad row
    float* __restrict__ c_fin)    // [H]
{
    __shared__ float Hbuf[2][H_DIM];       // double-buffered Hv
    __shared__ __align__(16) float zh_s[2][8];  // [half][6 used]
    const int tid  = threadIdx.x;          // 0..511
    const int lane = tid & 63;
    const int wv   = tid >> 6;             // wave 0..7
    const int h    = tid >> 1;             // 0..255
    const int half = tid & 1;              // 0: f,i   1: u,o
    const int l4   = lane * 4;

    // matvec columns for waves 0..5: cols cA=2w, cB=2w+1 (c = gate*3 + (j-1))
    float4 WA = make_float4(0,0,0,0), WB = WA;
    if (wv < 6) {
        const int cA = 2 * wv, cB = cA + 1;
        const int gA = cA / 3, jA = cA % 3 + 1;
        const int gB = cB / 3, jB = cB % 3 + 1;
        const float* WgA = (gA == 0) ? Wf : (gA == 1) ? Wi : (gA == 2) ? Wu : Wo;
        const float* WgB = (gB == 0) ? Wf : (gB == 1) ? Wi : (gB == 2) ? Wu : Wo;
        WA = *(const float4*)(WgA + jA * DH + 256 + l4);
        WB = *(const float4*)(WgB + jB * DH + 256 + l4);
    }

    float C = 0.0f, Hprev = 0.0f;
    if (tid < H_DIM) Hbuf[1][tid] = 0.0f;  // Hv[-1] = 0
    __syncthreads();

    // zx register double-buffer (depth 2): thread reads its half's 2 float4
    float4 za0, za1, zb0, zb1;
    {
        const float4* p0 = (const float4*)(zx + (long)h * NG) + half * 2;
        const float4* p1 = (const float4*)(zx + ((long)B_DIM + h) * NG) + half * 2;
        za0 = p0[0]; za1 = p0[1];
        zb0 = p1[0]; zb1 = p1[1];
    }

    auto step = [&](int t, float4& z0, float4& z1) {
        // early-issue global store of Hv[t-1] (half1 lanes; acks float)
        if (half) hv_tab[(long)(t - 1) * H_DIM + h] = Hprev;

        // ---- matvec: waves 0..5, 2 columns each
        if (wv < 6) {
            const float4 Hv4 = *(const float4*)&Hbuf[(t + 1) & 1][l4];
            float pA = fmaf(WA.x, Hv4.x, fmaf(WA.y, Hv4.y, fmaf(WA.z, Hv4.z, WA.w * Hv4.w)));
            float pB = fmaf(WB.x, Hv4.x, fmaf(WB.y, Hv4.y, fmaf(WB.z, Hv4.z, WB.w * Hv4.w)));
            pA = wsum(pA);
            pB = wsum(pB);
            if (lane == 63) {
                const int cA = 2 * wv;
                zh_s[cA / 6][cA % 6]             = pA;
                zh_s[(cA + 1) / 6][(cA + 1) % 6] = pB;
            }
        }
        lds_barrier();                      // zh + Hbuf(t-1) reads done below

        // ---- gates: this thread's 2 gates (half0: f,i ; half1: u,o)
        const float4 ZA = *(const float4*)&zh_s[half][0];
        const float2 ZB = *(const float2*)&zh_s[half][4];
        const float c1 = __cosf(z0.y + ZA.x), c2 = __cosf(z0.z + ZA.y), c3 = __cosf(z0.w + ZA.z);
        const float c4 = __cosf(z1.y + ZA.w), c5 = __cosf(z1.z + ZB.x), c6 = __cosf(z1.w + ZB.y);
        const float pA = c1 * c2 * c3, pB = c4 * c5 * c6;
        float gA, gB;
        if (half == 0) { gA = fast_sigmoid(pA); gB = fast_sigmoid(pB); }   // f, i
        else           { gA = fast_tanh(pA);    gB = fast_sigmoid(pB); }   // g, o
        const float oA = dpp_xor1(gA);        // partner's first value (VALU, ~8cy)
        const float oB = dpp_xor1(gB);        // partner's second value
        const float f_ = half ? oA : gA;
        const float i_ = half ? oB : gB;
        const float g_ = half ? gA : oA;
        const float o_ = half ? gB : oB;

        // prefetch zx[t+2] (floats across steps)
        {
            const int tp = (t + 2 < T_DIM) ? (t + 2) : t;
            const float4* pp = (const float4*)(zx + ((long)tp * B_DIM + h) * NG) + half * 2;
            z0 = pp[0]; z1 = pp[1];
        }

        C = fmaf(f_, C, i_ * g_);             // both halves redundant, bit-identical
        const float Hnew = o_ * fast_tanh(C);
        if (half == 0) Hbuf[t & 1][h] = Hnew;
        Hprev = Hnew;
        lds_barrier();                        // Hbuf(t) + zh WAR for next step
    };

    for (int t = 0; t < T_DIM; t += 2) {
        step(t,     za0, za1);
        step(t + 1, zb0, zb1);
    }

    if (half) {
        hv_tab[(long)(T_DIM - 1) * H_DIM + h] = Hprev;
        c_fin[h] = C;
    }
}

// -------------------- broadcast: out[t,b,:] = Hv[t,:]; tails hx=Hv[511], cx=Cfin
__global__ __launch_bounds__(256) void bc_kernel(
    const float* __restrict__ hv_tab, const float* __restrict__ c_fin,
    float* __restrict__ out)
{
    const int blk  = blockIdx.x;
    const int w    = threadIdx.x >> 6;
    const int lane = threadIdx.x & 63;

    const float* src;
    long base;
    int rbase;
    if (blk < 4 * T_DIM) {
        const int t = blk >> 2;
        rbase = (blk & 3) * 64;
        src = hv_tab + (long)t * H_DIM;
        base = (long)t * (B_DIM * H_DIM);
    } else {
        const int k = blk - 4 * T_DIM;        // 0..7
        rbase = (k & 3) * 64;
        src = (k < 4) ? (hv_tab + (long)(T_DIM - 1) * H_DIM) : c_fin;
        base = (long)T_DIM * (B_DIM * H_DIM) + (k < 4 ? 0 : (long)B_DIM * H_DIM);
    }
    const float4 v = ((const float4*)src)[lane];
    #pragma unroll
    for (int it = 0; it < 16; ++it) {
        const int row = rbase + w + 4 * it;
        ((float4*)(out + base + (long)row * H_DIM))[lane] = v;
    }
}

extern "C" void kernel_launch(void* const* d_in, const int* in_sizes, int n_in,
                              void* d_out, int out_size, void* d_ws, size_t ws_size,
                              hipStream_t stream) {
    (void)in_sizes; (void)n_in; (void)out_size; (void)ws_size;
    const float* x   = (const float*)d_in[0];
    const float* Wf  = (const float*)d_in[1];
    const float* bf  = (const float*)d_in[2];
    const float* phf = (const float*)d_in[3];
    const float* Wi  = (const float*)d_in[4];
    const float* bi  = (const float*)d_in[5];
    const float* phi = (const float*)d_in[6];
    const float* Wu  = (const float*)d_in[7];
    const float* bu  = (const float*)d_in[8];
    const float* phu = (const float*)d_in[9];
    const float* Wo  = (const float*)d_in[10];
    const float* bo  = (const float*)d_in[11];
    const float* pho = (const float*)d_in[12];

    float* zx     = (float*)d_ws;                          // T*B*16 f = 8.39 MB
    float* hv_pad = zx + (size_t)T_DIM * B_DIM * NG;       // 256 f scratch (t=0 store)
    float* hv_tab = hv_pad + H_DIM;                        // T*H f = 512 KB
    float* c_fin  = hv_tab + (size_t)T_DIM * H_DIM;        // H f = 1 KB

    zx_kernel<<<T_DIM, 256, 0, stream>>>(
        x, Wf, Wi, Wu, Wo, bf, bi, bu, bo, phf, phi, phu, pho, zx);

    rec_kernel<<<1, 512, 0, stream>>>(
        Wf, Wi, Wu, Wo, zx, hv_tab, c_fin);

    bc_kernel<<<4 * T_DIM + 8, 256, 0, stream>>>(hv_tab, c_fin, (float*)d_out);
}

// Round 5
// 599.612 us; speedup vs baseline: 1.0727x; 1.0001x over previous
//
#include <hip/hip_runtime.h>

// QuantumQLSTM on MI355X — R16 (= R15 with the compile fix): bc_kernel ->
// nontemporal stores via native clang vector type (__builtin_nontemporal_store
// rejects HIP_vector_type float4). rec and zx byte-identical to R14.
// Structure (R7+): outs[t,b,:] = Hv[t,:] (b-independent). zx precompute ->
// 1-block sequential rec -> broadcast.
//
// Experiment (from R15): ~200us of non-rec time is invariant since R7.
// H1: bc is secretly ~200us (134MB of stores rolling the 4MB per-XCD L2);
// nt stores bypass L2 -> total ~450. H2: fixed harness/graph overhead ->
// total ~600 unchanged -> non-rec is at its floor; go back to rec.
//
// History: R1 4250 -> R2 2010 -> R3 1516 -> R4 1443 -> R5 1426 -> R6 FAILED
// -> R7 758 (rec 484) -> R8 772 (498) -> R9 752 (477) -> R10 744 (468)
// -> R11 632 (rec 354) -> R12 infra -> R13 643 (rec 365, NEUTRAL)
// -> R14 600 (rec 339, zx tiled) -> R15 compile-fail (nt store on HIP float4)
// -> R16.

#define T_DIM 512
#define B_DIM 256
#define D_DIM 256
#define H_DIM 256
#define DH    512   // D + H
#define NG    16    // 4 gates * NQ(4)
#define XPAD  68    // Xc/Wc LDS row stride (floats): 16B-aligned, 2-way max

typedef float f32x4 __attribute__((ext_vector_type(4)));  // clang-native 16B vec

__device__ __forceinline__ float fast_sigmoid(float x) {
    return 1.0f / (1.0f + __expf(-x));
}
__device__ __forceinline__ float fast_tanh(float x) {
    // |x| <= ~2.1 here (|C| <= 0.557/(1-0.731)); exp safe
    float e = __expf(2.0f * x);
    return (e - 1.0f) / (e + 1.0f);
}
// x + dpp_mov(x): one reduction level, VALU pipe.
template <int CTRL, int RM, int BM, bool BC>
__device__ __forceinline__ float dadd(float x) {
    return x + __int_as_float(
        __builtin_amdgcn_update_dpp(0, __float_as_int(x), CTRL, RM, BM, BC));
}
// full-wave sum; result valid in lane 63
__device__ __forceinline__ float wsum(float x) {
    x = dadd<0x111, 0xf, 0xf, true >(x);   // row_shr:1
    x = dadd<0x112, 0xf, 0xf, true >(x);   // row_shr:2
    x = dadd<0x114, 0xf, 0xf, true >(x);   // row_shr:4
    x = dadd<0x118, 0xf, 0xf, true >(x);   // row_shr:8
    x = dadd<0x142, 0xa, 0xf, false>(x);   // row_bcast:15
    x = dadd<0x143, 0xc, 0xf, false>(x);   // row_bcast:31 -> lane63
    return x;
}
// lane^1 exchange on the VALU pipe: quad_perm [1,0,3,2] (replaces ds_bpermute)
__device__ __forceinline__ float dpp_xor1(float x) {
    return __int_as_float(
        __builtin_amdgcn_update_dpp(0, __float_as_int(x), 0xB1, 0xf, 0xf, true));
}
// Barrier draining ONLY the LDS pipe (no vmcnt): global ops float across steps.
__device__ __forceinline__ void lds_barrier() {
    __asm__ volatile("s_waitcnt lgkmcnt(0)\n\ts_barrier" ::: "memory");
}

// -------------------- zx precompute (R14: 4x4 register tiling; unchanged)
// zx[(t*B+b)*16+q] = b_q + phi_q + x_row . Wg[qj, 0:256]
__global__ __launch_bounds__(256) void zx_kernel(
    const float* __restrict__ x,
    const float* __restrict__ Wf, const float* __restrict__ Wi,
    const float* __restrict__ Wu, const float* __restrict__ Wo,
    const float* __restrict__ bf, const float* __restrict__ bi,
    const float* __restrict__ bu, const float* __restrict__ bo,
    const float* __restrict__ phf, const float* __restrict__ phi,
    const float* __restrict__ phu, const float* __restrict__ pho,
    float* __restrict__ zx)
{
    __shared__ float Xc[256][XPAD];
    __shared__ float Wc[NG][XPAD];
    const int tid = threadIdx.x;
    const int rt  = tid >> 2;           // 0..63
    const int qt  = tid & 3;            // gate index 0..3

    const float* bv = (qt == 0) ? bf : (qt == 1) ? bi : (qt == 2) ? bu : bo;
    const float* pv = (qt == 0) ? phf : (qt == 1) ? phi : (qt == 2) ? phu : pho;
    float acc[4][4];
    #pragma unroll
    for (int j = 0; j < 4; ++j) {
        const float bj = bv[j] + pv[j];
        acc[0][j] = bj; acc[1][j] = bj; acc[2][j] = bj; acc[3][j] = bj;
    }

    const long base = (long)blockIdx.x * 256 * D_DIM;

    for (int c = 0; c < 4; ++c) {                 // k-chunk of 64
        const int k0 = c * 64;
        #pragma unroll
        for (int it = 0; it < 16; ++it) {
            const int e = tid + it * 256;
            const int row = e >> 4, col4 = (e & 15) * 4;
            *(float4*)&Xc[row][col4] =
                *(const float4*)(x + base + (long)row * D_DIM + k0 + col4);
        }
        {
            const int q16 = tid >> 4, col4 = (tid & 15) * 4;
            const int g = q16 >> 2, qj = q16 & 3;
            const float* W = (g == 0) ? Wf : (g == 1) ? Wi : (g == 2) ? Wu : Wo;
            *(float4*)&Wc[q16][col4] = *(const float4*)(W + qj * DH + k0 + col4);
        }
        __syncthreads();

        #pragma unroll 4
        for (int kk = 0; kk < 16; ++kk) {
            const int k4 = kk * 4;
            float4 xv0 = *(float4*)&Xc[rt][k4];
            float4 xv1 = *(float4*)&Xc[rt +  64][k4];
            float4 xv2 = *(float4*)&Xc[rt + 128][k4];
            float4 xv3 = *(float4*)&Xc[rt + 192][k4];
            float4 wv0 = *(float4*)&Wc[4 * qt + 0][k4];
            float4 wv1 = *(float4*)&Wc[4 * qt + 1][k4];
            float4 wv2 = *(float4*)&Wc[4 * qt + 2][k4];
            float4 wv3 = *(float4*)&Wc[4 * qt + 3][k4];
            #pragma unroll
            for (int i = 0; i < 4; ++i) {
                const float4 xv = (i == 0) ? xv0 : (i == 1) ? xv1 : (i == 2) ? xv2 : xv3;
                acc[i][0] = fmaf(xv.x, wv0.x, fmaf(xv.y, wv0.y, fmaf(xv.z, wv0.z, fmaf(xv.w, wv0.w, acc[i][0]))));
                acc[i][1] = fmaf(xv.x, wv1.x, fmaf(xv.y, wv1.y, fmaf(xv.z, wv1.z, fmaf(xv.w, wv1.w, acc[i][1]))));
                acc[i][2] = fmaf(xv.x, wv2.x, fmaf(xv.y, wv2.y, fmaf(xv.z, wv2.z, fmaf(xv.w, wv2.w, acc[i][2]))));
                acc[i][3] = fmaf(xv.x, wv3.x, fmaf(xv.y, wv3.y, fmaf(xv.z, wv3.z, fmaf(xv.w, wv3.w, acc[i][3]))));
            }
        }
        __syncthreads();
    }

    const long orow = (long)blockIdx.x * 256;
    #pragma unroll
    for (int i = 0; i < 4; ++i) {
        *(float4*)&zx[(orow + rt + 64 * i) * NG + qt * 4] =
            make_float4(acc[i][0], acc[i][1], acc[i][2], acc[i][3]);
    }
}

// -------------------- sequential core: ONE block, 512 threads (8 waves)
// (R11 structure + DPP gate exchange; unchanged from R14, 339us verified)
__global__ __launch_bounds__(512) void rec_kernel(
    const float* __restrict__ Wf, const float* __restrict__ Wi,
    const float* __restrict__ Wu, const float* __restrict__ Wo,
    const float* __restrict__ zx,
    float* __restrict__ hv_tab,   // [T][H]; hv_tab[-H..-1] is a scratch pad row
    float* __restrict__ c_fin)    // [H]
{
    __shared__ float Hbuf[2][H_DIM];       // double-buffered Hv
    __shared__ __align__(16) float zh_s[2][8];  // [half][6 used]
    const int tid  = threadIdx.x;          // 0..511
    const int lane = tid & 63;
    const int wv   = tid >> 6;             // wave 0..7
    const int h    = tid >> 1;             // 0..255
    const int half = tid & 1;              // 0: f,i   1: u,o
    const int l4   = lane * 4;

    // matvec columns for waves 0..5: cols cA=2w, cB=2w+1 (c = gate*3 + (j-1))
    float4 WA = make_float4(0,0,0,0), WB = WA;
    if (wv < 6) {
        const int cA = 2 * wv, cB = cA + 1;
        const int gA = cA / 3, jA = cA % 3 + 1;
        const int gB = cB / 3, jB = cB % 3 + 1;
        const float* WgA = (gA == 0) ? Wf : (gA == 1) ? Wi : (gA == 2) ? Wu : Wo;
        const float* WgB = (gB == 0) ? Wf : (gB == 1) ? Wi : (gB == 2) ? Wu : Wo;
        WA = *(const float4*)(WgA + jA * DH + 256 + l4);
        WB = *(const float4*)(WgB + jB * DH + 256 + l4);
    }

    float C = 0.0f, Hprev = 0.0f;
    if (tid < H_DIM) Hbuf[1][tid] = 0.0f;  // Hv[-1] = 0
    __syncthreads();

    // zx register double-buffer (depth 2): thread reads its half's 2 float4
    float4 za0, za1, zb0, zb1;
    {
        const float4* p0 = (const float4*)(zx + (long)h * NG) + half * 2;
        const float4* p1 = (const float4*)(zx + ((long)B_DIM + h) * NG) + half * 2;
        za0 = p0[0]; za1 = p0[1];
        zb0 = p1[0]; zb1 = p1[1];
    }

    auto step = [&](int t, float4& z0, float4& z1) {
        // early-issue global store of Hv[t-1] (half1 lanes; acks float)
        if (half) hv_tab[(long)(t - 1) * H_DIM + h] = Hprev;

        // ---- matvec: waves 0..5, 2 columns each
        if (wv < 6) {
            const float4 Hv4 = *(const float4*)&Hbuf[(t + 1) & 1][l4];
            float pA = fmaf(WA.x, Hv4.x, fmaf(WA.y, Hv4.y, fmaf(WA.z, Hv4.z, WA.w * Hv4.w)));
            float pB = fmaf(WB.x, Hv4.x, fmaf(WB.y, Hv4.y, fmaf(WB.z, Hv4.z, WB.w * Hv4.w)));
            pA = wsum(pA);
            pB = wsum(pB);
            if (lane == 63) {
                const int cA = 2 * wv;
                zh_s[cA / 6][cA % 6]             = pA;
                zh_s[(cA + 1) / 6][(cA + 1) % 6] = pB;
            }
        }
        lds_barrier();                      // zh + Hbuf(t-1) reads done below

        // ---- gates: this thread's 2 gates (half0: f,i ; half1: u,o)
        const float4 ZA = *(const float4*)&zh_s[half][0];
        const float2 ZB = *(const float2*)&zh_s[half][4];
        const float c1 = __cosf(z0.y + ZA.x), c2 = __cosf(z0.z + ZA.y), c3 = __cosf(z0.w + ZA.z);
        const float c4 = __cosf(z1.y + ZA.w), c5 = __cosf(z1.z + ZB.x), c6 = __cosf(z1.w + ZB.y);
        const float pA = c1 * c2 * c3, pB = c4 * c5 * c6;
        float gA, gB;
        if (half == 0) { gA = fast_sigmoid(pA); gB = fast_sigmoid(pB); }   // f, i
        else           { gA = fast_tanh(pA);    gB = fast_sigmoid(pB); }   // g, o
        const float oA = dpp_xor1(gA);        // partner's first value (VALU, ~8cy)
        const float oB = dpp_xor1(gB);        // partner's second value
        const float f_ = half ? oA : gA;
        const float i_ = half ? oB : gB;
        const float g_ = half ? gA : oA;
        const float o_ = half ? gB : oB;

        // prefetch zx[t+2] (floats across steps)
        {
            const int tp = (t + 2 < T_DIM) ? (t + 2) : t;
            const float4* pp = (const float4*)(zx + ((long)tp * B_DIM + h) * NG) + half * 2;
            z0 = pp[0]; z1 = pp[1];
        }

        C = fmaf(f_, C, i_ * g_);             // both halves redundant, bit-identical
        const float Hnew = o_ * fast_tanh(C);
        if (half == 0) Hbuf[t & 1][h] = Hnew;
        Hprev = Hnew;
        lds_barrier();                        // Hbuf(t) + zh WAR for next step
    };

    for (int t = 0; t < T_DIM; t += 2) {
        step(t,     za0, za1);
        step(t + 1, zb0, zb1);
    }

    if (half) {
        hv_tab[(long)(T_DIM - 1) * H_DIM + h] = Hprev;
        c_fin[h] = C;
    }
}

// -------------------- broadcast: out[t,b,:] = Hv[t,:]; tails hx=Hv[511], cx=Cfin
// R16: nontemporal stores via clang-native f32x4 — out is write-once, never
// re-read on device; bypass L2 so 134 MB of streaming writes don't roll the
// 4 MB per-XCD L2.
__global__ __launch_bounds__(256) void bc_kernel(
    const float* __restrict__ hv_tab, const float* __restrict__ c_fin,
    float* __restrict__ out)
{
    const int blk  = blockIdx.x;
    const int w    = threadIdx.x >> 6;
    const int lane = threadIdx.x & 63;

    const float* src;
    long base;
    int rbase;
    if (blk < 4 * T_DIM) {
        const int t = blk >> 2;
        rbase = (blk & 3) * 64;
        src = hv_tab + (long)t * H_DIM;
        base = (long)t * (B_DIM * H_DIM);
    } else {
        const int k = blk - 4 * T_DIM;        // 0..7
        rbase = (k & 3) * 64;
        src = (k < 4) ? (hv_tab + (long)(T_DIM - 1) * H_DIM) : c_fin;
        base = (long)T_DIM * (B_DIM * H_DIM) + (k < 4 ? 0 : (long)B_DIM * H_DIM);
    }
    const f32x4 v = ((const f32x4*)src)[lane];
    #pragma unroll
    for (int it = 0; it < 16; ++it) {
        const int row = rbase + w + 4 * it;
        __builtin_nontemporal_store(
            v, (f32x4*)(out + base + (long)row * H_DIM) + lane);
    }
}

extern "C" void kernel_launch(void* const* d_in, const int* in_sizes, int n_in,
                              void* d_out, int out_size, void* d_ws, size_t ws_size,
                              hipStream_t stream) {
    (void)in_sizes; (void)n_in; (void)out_size; (void)ws_size;
    const float* x   = (const float*)d_in[0];
    const float* Wf  = (const float*)d_in[1];
    const float* bf  = (const float*)d_in[2];
    const float* phf = (const float*)d_in[3];
    const float* Wi  = (const float*)d_in[4];
    const float* bi  = (const float*)d_in[5];
    const float* phi = (const float*)d_in[6];
    const float* Wu  = (const float*)d_in[7];
    const float* bu  = (const float*)d_in[8];
    const float* phu = (const float*)d_in[9];
    const float* Wo  = (const float*)d_in[10];
    const float* bo  = (const float*)d_in[11];
    const float* pho = (const float*)d_in[12];

    float* zx     = (float*)d_ws;                          // T*B*16 f = 8.39 MB
    float* hv_pad = zx + (size_t)T_DIM * B_DIM * NG;       // 256 f scratch (t=0 store)
    float* hv_tab = hv_pad + H_DIM;                        // T*H f = 512 KB
    float* c_fin  = hv_tab + (size_t)T_DIM * H_DIM;        // H f = 1 KB

    zx_kernel<<<T_DIM, 256, 0, stream>>>(
        x, Wf, Wi, Wu, Wo, bf, bi, bu, bo, phf, phi, phu, pho, zx);

    rec_kernel<<<1, 512, 0, stream>>>(
        Wf, Wi, Wu, Wo, zx, hv_tab, c_fin);

    bc_kernel<<<4 * T_DIM + 8, 256, 0, stream>>>(hv_tab, c_fin, (float*)d_out);
}